// Round 3
// baseline (143.306 us; speedup 1.0000x reference)
//
#include <hip/hip_runtime.h>
#include <stdint.h>

#define N_ROWS 8192
#define FEAT   256
#define YSPLIT 32
#define CPB    (N_ROWS / YSPLIT)   // 256 cols per kmain block
#define CT     64                  // cols staged per chunk
#define BSTRIDE 280                // bytes per staged col: 70 dw = 6 mod 32 -> uniform banks, 8B-aligned

typedef float f32x4 __attribute__((ext_vector_type(4)));

// ---- Kernel 1: normalize rows -> fp8 e4m3 (x16 scaled); fused pos dot ----
__global__ void knorm(const float* __restrict__ feat,
                      uint32_t* __restrict__ f8,
                      float* __restrict__ pos) {
    __shared__ float ex[4][FEAT];
    int wave = threadIdx.x >> 6;
    int lane = threadIdx.x & 63;
    int row  = blockIdx.x * 4 + wave;
    float4 v = ((const float4*)(feat + row * FEAT))[lane];
    float ss = v.x*v.x + v.y*v.y + v.z*v.z + v.w*v.w;
    #pragma unroll
    for (int off = 1; off < 64; off <<= 1) ss += __shfl_xor(ss, off);
    float inv = 1.0f / fmaxf(sqrtf(ss), 1e-12f);
    float4 o; o.x = v.x*inv; o.y = v.y*inv; o.z = v.z*inv; o.w = v.w*inv;
    // scale by 16: entries ~N(0,1) -> e4m3 normal range (rel err ~3.6%)
    const float s = 16.0f;
    uint32_t p = __builtin_amdgcn_cvt_pk_fp8_f32(o.x*s, o.y*s, 0, false);
    p = __builtin_amdgcn_cvt_pk_fp8_f32(o.z*s, o.w*s, p, true);
    f8[row * (FEAT/4) + lane] = p;
    // exchange normalized rows for the fp32 positive dot
    ((float4*)ex[wave])[lane] = o;
    __syncthreads();
    float4 q = ((float4*)ex[wave ^ 1])[lane];
    float d = o.x*q.x + o.y*q.y + o.z*q.z + o.w*q.w;
    #pragma unroll
    for (int off = 1; off < 64; off <<= 1) d += __shfl_xor(d, off);
    if (lane == 0) pos[row] = d;
}

// ---- Kernel 2: fp8 f@f^T with fused fixed-max exp-sum --------------------
// grid (16, YSPLIT): x = row-block of 512 rows (8 waves x 64 rows/wave),
//                    y = column split of CPB cols.
// acc = 256*s (x16-scaled operands); sum exp2(acc*Kc/256 - Kc).
__global__ __launch_bounds__(512, 4)
void kmain(const uint8_t* __restrict__ f8, float* __restrict__ partial) {
    __shared__ uint8_t Bs[CT * BSTRIDE];   // 17,920 B
    const int t    = threadIdx.x;
    const int lane = t & 63;
    const int wave = t >> 6;
    const int quad = lane >> 4;
    const int l15  = lane & 15;
    const int rw    = blockIdx.x * 512 + wave * 64;
    const int cbase = blockIdx.y * CPB;
    const float Kc = 20.60992915555662f;   // log2(e)/0.07
    const float Ks = Kc / 256.0f;          // acc carries 256*s

    // A frags: 64 rows x K=256 fp8 resident in registers (64 VGPRs)
    long af[4][8];
    #pragma unroll
    for (int rg = 0; rg < 4; ++rg)
        #pragma unroll
        for (int ks = 0; ks < 8; ++ks)
            af[rg][ks] = *(const long*)(f8 + (rw + rg*16 + l15) * FEAT + ks*32 + quad*8);

    float lsum[4][4] = {};

    for (int ct = 0; ct < CPB / CT; ++ct) {
        __syncthreads();
        const int c0 = cbase + ct * CT;
        {   // stage 64 cols x 256 B: 512 threads x 32 B (b64 LDS writes, 8B-aligned)
            int col = t >> 3;
            int o   = (t & 7) * 32;
            const ulonglong2* src = (const ulonglong2*)(f8 + (c0 + col) * FEAT + o);
            ulonglong2 w0 = src[0];
            ulonglong2 w1 = src[1];
            uint64_t* dst = (uint64_t*)(Bs + col * BSTRIDE + o);
            dst[0] = w0.x; dst[1] = w0.y; dst[2] = w1.x; dst[3] = w1.y;
        }
        __syncthreads();

        #pragma unroll
        for (int g = 0; g < 4; ++g) {
            f32x4 acc[4] = {{0,0,0,0},{0,0,0,0},{0,0,0,0},{0,0,0,0}};
            #pragma unroll
            for (int ks = 0; ks < 8; ++ks) {
                long b = *(const long*)(Bs + (g*16 + l15) * BSTRIDE + ks*32 + quad*8);
                #pragma unroll
                for (int rg = 0; rg < 4; ++rg)
                    acc[rg] = __builtin_amdgcn_mfma_f32_16x16x32_fp8_fp8(af[rg][ks], b, acc[rg], 0, 0, 0);
            }
            const int cg = c0 + g * 16;
            #pragma unroll
            for (int rg = 0; rg < 4; ++rg) {
                const bool dg = (cg == rw + rg * 16);   // wave-uniform diag block
                #pragma unroll
                for (int r = 0; r < 4; ++r) {
                    float e = __builtin_amdgcn_exp2f(fmaf(acc[rg][r], Ks, -Kc));
                    if (dg && l15 == quad * 4 + r) e = 0.f;   // mask j == i
                    lsum[rg][r] += e;
                }
            }
        }
    }

    // reduce across the 16 col-lanes sharing each row
    #pragma unroll
    for (int rg = 0; rg < 4; ++rg)
        #pragma unroll
        for (int r = 0; r < 4; ++r) {
            float v = lsum[rg][r];
            v += __shfl_xor(v, 1);
            v += __shfl_xor(v, 2);
            v += __shfl_xor(v, 4);
            v += __shfl_xor(v, 8);
            lsum[rg][r] = v;
        }
    if (l15 == 0) {
        #pragma unroll
        for (int rg = 0; rg < 4; ++rg)
            #pragma unroll
            for (int r = 0; r < 4; ++r)
                partial[blockIdx.y * N_ROWS + rw + rg*16 + quad*4 + r] = lsum[rg][r];
    }
}

// ---- Kernel 3: per-row loss + block tree-reduce --------------------------
__global__ void kreduce(const float* __restrict__ partial,
                        const float* __restrict__ pos,
                        float* __restrict__ bsum) {
    __shared__ float red[4];
    int row  = blockIdx.x * 256 + threadIdx.x;
    int wave = threadIdx.x >> 6;
    int lane = threadIdx.x & 63;
    float L = 0.f;
    #pragma unroll
    for (int p = 0; p < YSPLIT; ++p) L += partial[p * N_ROWS + row];
    const float invT = 14.285714285714286f;
    float loss = invT * (1.0f - pos[row])
               + 0.6931471805599453f * __builtin_amdgcn_logf(L);
    #pragma unroll
    for (int off = 1; off < 64; off <<= 1) loss += __shfl_xor(loss, off);
    if (lane == 0) red[wave] = loss;
    __syncthreads();
    if (threadIdx.x == 0)
        bsum[blockIdx.x] = red[0] + red[1] + red[2] + red[3];
}

// ---- Kernel 4: final 32 -> 1 ---------------------------------------------
__global__ void kfinal(const float* __restrict__ bsum, float* __restrict__ out) {
    int lane = threadIdx.x;
    float v = (lane < 32) ? bsum[lane] : 0.f;
    #pragma unroll
    for (int off = 1; off < 32; off <<= 1) v += __shfl_xor(v, off);
    if (lane == 0) out[0] = v * (1.0f / 8192.0f);
}

extern "C" void kernel_launch(void* const* d_in, const int* in_sizes, int n_in,
                              void* d_out, int out_size, void* d_ws, size_t ws_size,
                              hipStream_t stream) {
    const float* feat = (const float*)d_in[0];
    float* out = (float*)d_out;
    char* ws = (char*)d_ws;
    uint32_t* f8      = (uint32_t*)ws;                                // 2 MB fp8
    float*    partial = (float*)(ws + (2u << 20));                    // 1 MB
    float*    pos     = (float*)(ws + (3u << 20));                    // 32 KB
    float*    bsum    = (float*)(ws + (3u << 20) + (1u << 15));       // 128 B

    knorm<<<N_ROWS / 4, 256, 0, stream>>>(feat, f8, pos);
    kmain<<<dim3(16, YSPLIT), 512, 0, stream>>>((const uint8_t*)f8, partial);
    kreduce<<<N_ROWS / 256, 256, 0, stream>>>(partial, pos, bsum);
    kfinal<<<1, 64, 0, stream>>>(bsum, out);
}

// Round 4
// 104.503 us; speedup vs baseline: 1.3713x; 1.3713x over previous
//
#include <hip/hip_runtime.h>
#include <stdint.h>

#define N_ROWS 8192
#define FEAT   256
#define YSPLIT 32
#define CPB    (N_ROWS / YSPLIT)   // 256 cols per kmain block
#define CT     64                  // cols staged per chunk
#define BSTRIDE 280                // bytes/col: 70 dw = 6 mod 32 -> conflict-free even banks

typedef float f32x4 __attribute__((ext_vector_type(4)));

// ---- Kernel 1: normalize rows -> fp8 e4m3 (x16 scaled); fused pos dot ----
__global__ void knorm(const float* __restrict__ feat,
                      uint32_t* __restrict__ f8,
                      float* __restrict__ pos) {
    __shared__ float ex[4][FEAT];
    int wave = threadIdx.x >> 6;
    int lane = threadIdx.x & 63;
    int row  = blockIdx.x * 4 + wave;
    float4 v = ((const float4*)(feat + row * FEAT))[lane];
    float ss = v.x*v.x + v.y*v.y + v.z*v.z + v.w*v.w;
    #pragma unroll
    for (int off = 1; off < 64; off <<= 1) ss += __shfl_xor(ss, off);
    float inv = 1.0f / fmaxf(sqrtf(ss), 1e-12f);
    float4 o; o.x = v.x*inv; o.y = v.y*inv; o.z = v.z*inv; o.w = v.w*inv;
    const float s = 16.0f;   // ~N(0,1/16) entries -> e4m3 sweet range
    uint32_t p = __builtin_amdgcn_cvt_pk_fp8_f32(o.x*s, o.y*s, 0, false);
    p = __builtin_amdgcn_cvt_pk_fp8_f32(o.z*s, o.w*s, p, true);
    f8[row * (FEAT/4) + lane] = p;
    ((float4*)ex[wave])[lane] = o;
    __syncthreads();
    float4 q = ((float4*)ex[wave ^ 1])[lane];
    float d = o.x*q.x + o.y*q.y + o.z*q.z + o.w*q.w;
    #pragma unroll
    for (int off = 1; off < 64; off <<= 1) d += __shfl_xor(d, off);
    if (lane == 0) pos[row] = d;
}

// ---- Kernel 2: fp8 f@f^T with fused fixed-max exp-sum --------------------
// grid (32, YSPLIT): x = row-block of 256 rows (4 waves x 64 rows/wave),
//                    y = column split of CPB cols.
// 256-thread blocks + (256,3): 170-VGPR cap, ~125 needed -> NO SPILL,
// 3 blocks/CU (LDS 3 x 17.9 KB, 1 wave/SIMD granularity).
__global__ __launch_bounds__(256, 3)
void kmain(const uint8_t* __restrict__ f8, float* __restrict__ partial) {
    __shared__ uint8_t Bs[CT * BSTRIDE];   // 17,920 B
    const int t    = threadIdx.x;
    const int lane = t & 63;
    const int wave = t >> 6;          // 0..3
    const int quad = lane >> 4;
    const int l15  = lane & 15;
    const int rw    = blockIdx.x * 256 + wave * 64;
    const int cbase = blockIdx.y * CPB;
    const float Kc = 20.60992915555662f;   // log2(e)/0.07
    const float Ks = Kc / 256.0f;          // acc carries 256*s (x16 * x16)

    // A frags: 64 rows x K=256 fp8 resident in registers (64 VGPRs)
    long af[4][8];
    #pragma unroll
    for (int rg = 0; rg < 4; ++rg)
        #pragma unroll
        for (int ks = 0; ks < 8; ++ks)
            af[rg][ks] = *(const long*)(f8 + (rw + rg*16 + l15) * FEAT + ks*32 + quad*8);

    float lsum[4][4] = {};

    for (int ct = 0; ct < CPB / CT; ++ct) {
        __syncthreads();
        const int c0 = cbase + ct * CT;
        {   // stage 64 cols x 256 B with 256 threads x 64 B
            int col = t >> 2;
            int o   = (t & 3) * 64;
            const ulonglong2* src = (const ulonglong2*)(f8 + (c0 + col) * FEAT + o);
            ulonglong2 w0 = src[0];
            ulonglong2 w1 = src[1];
            ulonglong2 w2 = src[2];
            ulonglong2 w3 = src[3];
            uint64_t* dst = (uint64_t*)(Bs + col * BSTRIDE + o);
            dst[0] = w0.x; dst[1] = w0.y; dst[2] = w1.x; dst[3] = w1.y;
            dst[4] = w2.x; dst[5] = w2.y; dst[6] = w3.x; dst[7] = w3.y;
        }
        __syncthreads();

        #pragma unroll
        for (int g = 0; g < 4; ++g) {
            f32x4 acc[4] = {{0,0,0,0},{0,0,0,0},{0,0,0,0},{0,0,0,0}};
            #pragma unroll
            for (int ks = 0; ks < 8; ++ks) {
                long b = *(const long*)(Bs + (g*16 + l15) * BSTRIDE + ks*32 + quad*8);
                #pragma unroll
                for (int rg = 0; rg < 4; ++rg)
                    acc[rg] = __builtin_amdgcn_mfma_f32_16x16x32_fp8_fp8(af[rg][ks], b, acc[rg], 0, 0, 0);
            }
            const int cg = c0 + g * 16;
            #pragma unroll
            for (int rg = 0; rg < 4; ++rg) {
                const bool dg = (cg == rw + rg * 16);   // wave-uniform diag block
                #pragma unroll
                for (int r = 0; r < 4; ++r) {
                    float e = __builtin_amdgcn_exp2f(fmaf(acc[rg][r], Ks, -Kc));
                    if (dg && l15 == quad * 4 + r) e = 0.f;   // mask j == i
                    lsum[rg][r] += e;
                }
            }
        }
    }

    // reduce across the 16 col-lanes sharing each row
    #pragma unroll
    for (int rg = 0; rg < 4; ++rg)
        #pragma unroll
        for (int r = 0; r < 4; ++r) {
            float v = lsum[rg][r];
            v += __shfl_xor(v, 1);
            v += __shfl_xor(v, 2);
            v += __shfl_xor(v, 4);
            v += __shfl_xor(v, 8);
            lsum[rg][r] = v;
        }
    if (l15 == 0) {
        #pragma unroll
        for (int rg = 0; rg < 4; ++rg)
            #pragma unroll
            for (int r = 0; r < 4; ++r)
                partial[blockIdx.y * N_ROWS + rw + rg*16 + quad*4 + r] = lsum[rg][r];
    }
}

// ---- Kernel 3: per-row loss + block tree-reduce --------------------------
__global__ void kreduce(const float* __restrict__ partial,
                        const float* __restrict__ pos,
                        float* __restrict__ bsum) {
    __shared__ float red[4];
    int row  = blockIdx.x * 256 + threadIdx.x;
    int wave = threadIdx.x >> 6;
    int lane = threadIdx.x & 63;
    float L = 0.f;
    #pragma unroll
    for (int p = 0; p < YSPLIT; ++p) L += partial[p * N_ROWS + row];
    const float invT = 14.285714285714286f;
    float loss = invT * (1.0f - pos[row])
               + 0.6931471805599453f * __builtin_amdgcn_logf(L);
    #pragma unroll
    for (int off = 1; off < 64; off <<= 1) loss += __shfl_xor(loss, off);
    if (lane == 0) red[wave] = loss;
    __syncthreads();
    if (threadIdx.x == 0)
        bsum[blockIdx.x] = red[0] + red[1] + red[2] + red[3];
}

// ---- Kernel 4: final 32 -> 1 ---------------------------------------------
__global__ void kfinal(const float* __restrict__ bsum, float* __restrict__ out) {
    int lane = threadIdx.x;
    float v = (lane < 32) ? bsum[lane] : 0.f;
    #pragma unroll
    for (int off = 1; off < 32; off <<= 1) v += __shfl_xor(v, off);
    if (lane == 0) out[0] = v * (1.0f / 8192.0f);
}

extern "C" void kernel_launch(void* const* d_in, const int* in_sizes, int n_in,
                              void* d_out, int out_size, void* d_ws, size_t ws_size,
                              hipStream_t stream) {
    const float* feat = (const float*)d_in[0];
    float* out = (float*)d_out;
    char* ws = (char*)d_ws;
    uint32_t* f8      = (uint32_t*)ws;                                // 2 MB fp8
    float*    partial = (float*)(ws + (2u << 20));                    // 1 MB
    float*    pos     = (float*)(ws + (3u << 20));                    // 32 KB
    float*    bsum    = (float*)(ws + (3u << 20) + (1u << 15));       // 128 B

    knorm<<<N_ROWS / 4, 256, 0, stream>>>(feat, f8, pos);
    kmain<<<dim3(32, YSPLIT), 256, 0, stream>>>((const uint8_t*)f8, partial);
    kreduce<<<N_ROWS / 256, 256, 0, stream>>>(partial, pos, bsum);
    kfinal<<<1, 64, 0, stream>>>(bsum, out);
}